// Round 16
// baseline (418.291 us; speedup 1.0000x reference)
//
#include <hip/hip_runtime.h>
#include <math.h>

// DifferentiableMultiMLPRenderer — round 16: barrier-free wave-independent renderer.
// Each wave owns 16 pixels end-to-end: gather+blend -> L1(emb in-reg MFMA) ->
// L2 -> L3, all in an 8KB private LDS slice (blend -> h1 -> h2 in place).
// No __syncthreads anywhere; 4 blocks/CU x 4 waves = 16 independent waves/CU.
// emb computed straight into A-fragments (lane-local: row=l15, k=kq*8+i).

typedef _Float16 hv8 __attribute__((ext_vector_type(8)));
typedef __attribute__((ext_vector_type(4))) float f32x4;

#define TILE_M 64   // pixels per block (16 per wave)

__device__ inline int swzW(int row, int k) { return row * 256 + (k ^ ((row & 7) << 3)); }
__device__ inline int swzA(int row, int k) { return row * 384 + (k ^ ((row & 7) << 3)); }

// ---- prep: fold style into b1; build f16 weights: w1T (1/3 folded), w2T, w3T ----
__global__ __launch_bounds__(256)
void prep_weights(const float* __restrict__ style,
                  const float* __restrict__ w1, const float* __restrict__ b1,
                  const float* __restrict__ w2, const float* __restrict__ w3,
                  _Float16* __restrict__ w1T, _Float16* __restrict__ w2T,
                  _Float16* __restrict__ w3T, float* __restrict__ b1p)
{
    const int j = blockIdx.x;
    const int t = threadIdx.x;
    if (j < 256) {
        float part = style[t] * w1[(size_t)(447 + t) * 256 + j];
        #pragma unroll
        for (int off = 32; off; off >>= 1) part += __shfl_down(part, off, 64);
        __shared__ float red[4];
        if ((t & 63) == 0) red[t >> 6] = part;
        __syncthreads();
        if (t == 0) b1p[j] = b1[j] + red[0] + red[1] + red[2] + red[3];
        for (int k = t; k < 448; k += 256) {
            float v = (k < 447) ? w1[(size_t)k * 256 + j] : 0.0f;
            if (k < 384) v *= (1.0f / 3.0f);
            w1T[(size_t)j * 448 + k] = (_Float16)v;
        }
    } else if (j < 512) {
        const int jj = j - 256;
        w2T[(size_t)jj * 256 + t] = (_Float16)w2[(size_t)t * 256 + jj];
    } else {
        #pragma unroll
        for (int r = 0; r < 16; ++r)
            w3T[r * 256 + t] = (r < 3) ? (_Float16)w3[t * 3 + r] : (_Float16)0.0f;
    }
}

// ---- pgemm: P[v][j] = sum_k [feat|shape][v][k] * w1T[j][k] (1/3 folded) ----
__global__ __launch_bounds__(256, 2)
void pgemm(const float* __restrict__ feat, const float* __restrict__ shp,
           const _Float16* __restrict__ w1T, _Float16* __restrict__ P, int nV)
{
    __shared__ _Float16 as[64 * 384];   // 48 KB
    const int tid = threadIdx.x;
    const int n0 = blockIdx.x * 64;
    const int lane = tid & 63, wv = tid >> 6;
    const int nbase = wv << 6, l15 = lane & 15, kq = lane >> 4;

    const hv8* bp[4];
    #pragma unroll
    for (int nf = 0; nf < 4; ++nf)
        bp[nf] = (const hv8*)(w1T + (size_t)(nbase + nf * 16 + l15) * 448 + (kq << 3));
    hv8 bv[3][4];
    auto loadB = [&](int t, hv8* dst) {
        #pragma unroll
        for (int nf = 0; nf < 4; ++nf) dst[nf] = bp[nf][t << 2];
    };
    loadB(0, bv[0]); loadB(1, bv[1]); loadB(2, bv[2]);

    #pragma unroll
    for (int i = 0; i < 12; ++i) {
        const int id = tid + i * 256;
        const int row = id / 48;
        const int g = id - row * 48;
        int v = n0 + row; if (v >= nV) v = nV - 1;
        const float* s = (g < 32) ? (feat + (size_t)v * 256 + g * 8)
                                  : (shp  + (size_t)v * 128 + (g - 32) * 8);
        const float4 a = ((const float4*)s)[0];
        const float4 b = ((const float4*)s)[1];
        hv8 h = { (_Float16)a.x, (_Float16)a.y, (_Float16)a.z, (_Float16)a.w,
                  (_Float16)b.x, (_Float16)b.y, (_Float16)b.z, (_Float16)b.w };
        *(hv8*)(&as[swzA(row, g * 8)]) = h;
    }
    f32x4 acc[4][4];
    #pragma unroll
    for (int mf = 0; mf < 4; ++mf)
        #pragma unroll
        for (int nf = 0; nf < 4; ++nf) acc[mf][nf] = (f32x4){0.f, 0.f, 0.f, 0.f};
    __syncthreads();

    auto loadA = [&](int t, hv8* dst) {
        #pragma unroll
        for (int mf = 0; mf < 4; ++mf)
            dst[mf] = *(const hv8*)(as + swzA(mf * 16 + l15, (t << 5) | (kq << 3)));
    };
    hv8 av[2][4];
    loadA(0, av[0]);
    #pragma unroll
    for (int t = 0; t < 12; ++t) {
        if (t + 1 < 12) loadA(t + 1, av[(t + 1) & 1]);
        const hv8* avt = av[t & 1];
        const hv8* bvt = bv[t % 3];
        __builtin_amdgcn_s_setprio(1);
        #pragma unroll
        for (int mf = 0; mf < 4; ++mf)
            #pragma unroll
            for (int nf = 0; nf < 4; ++nf)
                acc[mf][nf] = __builtin_amdgcn_mfma_f32_16x16x32_f16(avt[mf], bvt[nf], acc[mf][nf], 0, 0, 0);
        __builtin_amdgcn_s_setprio(0);
        if (t + 3 < 12) loadB(t + 3, bv[t % 3]);
    }
    #pragma unroll
    for (int mf = 0; mf < 4; ++mf)
        #pragma unroll
        for (int nf = 0; nf < 4; ++nf) {
            const int col = nbase + nf * 16 + l15;
            const int r0 = mf * 16 + (kq << 2);
            #pragma unroll
            for (int r = 0; r < 4; ++r) {
                const int v = n0 + r0 + r;
                if (v < nV) P[(size_t)v * 256 + col] = (_Float16)acc[mf][nf][r];
            }
        }
}

// ---- main fused pixel kernel: 256 thr / 4 waves; each wave independent ----
__global__ __launch_bounds__(256, 4)
void renderer(const int* __restrict__ pix, const float* __restrict__ bary,
              const int* __restrict__ faces,
              const _Float16* __restrict__ P,
              const float* __restrict__ color_bg,
              const float* __restrict__ b2g,
              const float* __restrict__ b3g,
              const _Float16* __restrict__ w1T,
              const _Float16* __restrict__ w2T,
              const _Float16* __restrict__ w3T,
              const float* __restrict__ b1p,
              float* __restrict__ out)
{
    __shared__ _Float16 pbAll[4][16 * 256];   // 32 KB: per-wave 8KB slice
    __shared__ int   vidx[4][16][3];
    __shared__ float bcs[4][16][3];

    const int tid  = threadIdx.x;
    const int lane = tid & 63;
    const int wv   = tid >> 6;           // 0..3
    const int cpx  = gridDim.x >> 3;
    const int bid  = (blockIdx.x & 7) * cpx + (blockIdx.x >> 3);   // XCD-aware
    const int n0   = bid * TILE_M + wv * 16;   // this wave's 16 pixels
    const int l15  = lane & 15;
    const int kq   = lane >> 4;
    _Float16* pbw = &pbAll[wv][0];

    // per-wave pixel metadata (lanes 0-15), wave-local visibility via lgkmcnt
    if (lane < 16) {
        const int n = n0 + lane;
        const int face = pix[n];
        vidx[wv][lane][0] = faces[face * 3 + 0];
        vidx[wv][lane][1] = faces[face * 3 + 1];
        vidx[wv][lane][2] = faces[face * 3 + 2];
        bcs[wv][lane][0] = bary[n * 3 + 0];
        bcs[wv][lane][1] = bary[n * 3 + 1];
        bcs[wv][lane][2] = bary[n * 3 + 2];
    }
    asm volatile("s_waitcnt lgkmcnt(0)" ::: "memory");

    // issue first two gather batches immediately (latency hides under emb VALU)
    const int gp = lane >> 5;            // 0..1
    const int c8 = (lane & 31) << 3;
    hv8 g0[3], g1[3];
    auto loadG = [&](hv8* g, int b) {
        const int p = (b << 1) + gp;
        g[0] = *(const hv8*)(P + (size_t)vidx[wv][p][0] * 256 + c8);
        g[1] = *(const hv8*)(P + (size_t)vidx[wv][p][1] * 256 + c8);
        g[2] = *(const hv8*)(P + (size_t)vidx[wv][p][2] * 256 + c8);
    };
    loadG(g0, 0);
    loadG(g1, 1);

    // b1 bias folded into the blend (per-lane col chunk)
    const float4 bb0 = *(const float4*)(b1p + c8);
    const float4 bb1 = *(const float4*)(b1p + c8 + 4);
    const hv8 b1h = { (_Float16)bb0.x, (_Float16)bb0.y, (_Float16)bb0.z, (_Float16)bb0.w,
                      (_Float16)bb1.x, (_Float16)bb1.y, (_Float16)bb1.z, (_Float16)bb1.w };

    // --- emb straight into A-fragments: lane (l15,kq) = pixel l15, k-slots kq*8+i ---
    hv8 ave[2];
    {
        const float c0 = bcs[wv][l15][0], c1 = bcs[wv][l15][1], c2 = bcs[wv][l15][2];
        #pragma unroll
        for (int t = 0; t < 2; ++t) {
            #pragma unroll
            for (int i = 0; i < 8; ++i) {
                const int s = (t << 5) + (kq << 3) + i;
                float v;
                if (s < 3) v = (s == 0) ? c0 : ((s == 1) ? c1 : c2);
                else if (s < 63) {
                    const int q = s - 3;
                    const int f = q / 6;
                    const int rem = q - f * 6;
                    const int d = (rem >= 3) ? rem - 3 : rem;
                    const float bd = (d == 0) ? c0 : ((d == 1) ? c1 : c2);
                    const float arg = bd * (float)(1 << f);
                    v = (rem < 3) ? __sinf(arg) : __cosf(arg);
                } else v = 0.0f;
                ave[t][i] = (_Float16)v;
            }
        }
    }

    // --- gather drain: 8 batches x 2 px, 2-deep ping-pong; blend+bias -> pbw ---
    auto blendG = [&](hv8* g, int b) {
        const int p = (b << 1) + gp;
        const _Float16 d0 = (_Float16)bcs[wv][p][0];
        const _Float16 d1 = (_Float16)bcs[wv][p][1];
        const _Float16 d2 = (_Float16)bcs[wv][p][2];
        *(hv8*)(&pbw[swzW(p, c8)]) = g[0] * d0 + g[1] * d1 + g[2] * d2 + b1h;
    };
    blendG(g0, 0); loadG(g0, 2);
    blendG(g1, 1); loadG(g1, 3);
    blendG(g0, 2); loadG(g0, 4);
    blendG(g1, 3); loadG(g1, 5);
    blendG(g0, 4); loadG(g0, 6);
    blendG(g1, 5); loadG(g1, 7);
    blendG(g0, 6);
    blendG(g1, 7);
    asm volatile("s_waitcnt lgkmcnt(0)" ::: "memory");   // blends visible to all lanes

    // --- layer 1: per col-half, acc init from blend (C-layout), emb MFMA on top ---
    #pragma unroll
    for (int h = 0; h < 2; ++h) {
        const int cb = h << 7;
        f32x4 acc[8];
        #pragma unroll
        for (int n = 0; n < 8; ++n) {
            const int col = cb + n * 16 + l15;
            const int r0 = kq << 2;
            #pragma unroll
            for (int r = 0; r < 4; ++r)
                acc[n][r] = (float)pbw[swzW(r0 + r, col)];
        }
        #pragma unroll
        for (int t = 0; t < 2; ++t) {
            __builtin_amdgcn_s_setprio(1);
            #pragma unroll
            for (int n = 0; n < 8; ++n) {
                const hv8 bve = *(const hv8*)(w1T + (size_t)(cb + n * 16 + l15) * 448 + 384 + (t << 5) + (kq << 3));
                acc[n] = __builtin_amdgcn_mfma_f32_16x16x32_f16(ave[t], bve, acc[n], 0, 0, 0);
            }
            __builtin_amdgcn_s_setprio(0);
        }
        // h1 = relu(acc) overwrites the same cols
        #pragma unroll
        for (int n = 0; n < 8; ++n) {
            const int col = cb + n * 16 + l15;
            const int r0 = kq << 2;
            #pragma unroll
            for (int r = 0; r < 4; ++r)
                pbw[swzW(r0 + r, col)] = (_Float16)fmaxf(acc[n][r], 0.0f);
        }
    }
    asm volatile("s_waitcnt lgkmcnt(0)" ::: "memory");   // h1 visible

    // --- layer 2: whole h1 A-slice into regs (32 VGPR) then h2 overwrites pbw ---
    hv8 avh[8];
    #pragma unroll
    for (int t = 0; t < 8; ++t)
        avh[t] = *(const hv8*)(pbw + swzW(l15, (t << 5) | (kq << 3)));
    #pragma unroll
    for (int h = 0; h < 2; ++h) {
        const int cb = h << 7;
        f32x4 acc[8];
        #pragma unroll
        for (int n = 0; n < 8; ++n) {
            const float b = b2g[cb + n * 16 + l15];
            acc[n] = (f32x4){b, b, b, b};
        }
        #pragma unroll
        for (int t = 0; t < 8; ++t) {
            __builtin_amdgcn_s_setprio(1);
            #pragma unroll
            for (int n = 0; n < 8; ++n) {
                const hv8 bv = *(const hv8*)(w2T + (size_t)(cb + n * 16 + l15) * 256 + (t << 5) + (kq << 3));
                acc[n] = __builtin_amdgcn_mfma_f32_16x16x32_f16(avh[t], bv, acc[n], 0, 0, 0);
            }
            __builtin_amdgcn_s_setprio(0);
        }
        #pragma unroll
        for (int n = 0; n < 8; ++n) {
            const int col = cb + n * 16 + l15;
            const int r0 = kq << 2;
            #pragma unroll
            for (int r = 0; r < 4; ++r)
                pbw[swzW(r0 + r, col)] = (_Float16)fmaxf(acc[n][r], 0.0f);
        }
    }
    asm volatile("s_waitcnt lgkmcnt(0)" ::: "memory");   // h2 visible

    // --- layer 3 MFMA (16 px x 4 ch) + composite ---
    f32x4 acc3 = (f32x4){0.f, 0.f, 0.f, 0.f};
    #pragma unroll
    for (int t = 0; t < 8; ++t) {
        const hv8 a3 = *(const hv8*)(pbw + swzW(l15, (t << 5) | (kq << 3)));
        const hv8 b3v = *(const hv8*)(w3T + l15 * 256 + (t << 5) + (kq << 3));
        acc3 = __builtin_amdgcn_mfma_f32_16x16x32_f16(a3, b3v, acc3, 0, 0, 0);
    }
    if (l15 < 4) {
        const int ch = l15;
        #pragma unroll
        for (int r = 0; r < 4; ++r) {
            const int p = (kq << 2) + r;
            const int n = n0 + p;
            const bool m = pix[n] > 0;
            float v;
            if (ch == 3) v = m ? 1.0f : 0.0f;
            else         v = m ? (fmaxf(acc3[r] + b3g[ch], 0.0f) - 1.0f)
                               : color_bg[(n >> 16) * 3 + ch];
            out[(size_t)n * 4 + ch] = v;
        }
    }
}

extern "C" void kernel_launch(void* const* d_in, const int* in_sizes, int n_in,
                              void* d_out, int out_size, void* d_ws, size_t ws_size,
                              hipStream_t stream) {
    const int*   pix      = (const int*)  d_in[0];
    const float* bary     = (const float*)d_in[1];
    const int*   faces    = (const int*)  d_in[2];
    const float* feature  = (const float*)d_in[3];
    const float* shapef   = (const float*)d_in[4];
    const float* color_bg = (const float*)d_in[5];
    const float* style    = (const float*)d_in[6];
    const float* w1       = (const float*)d_in[7];
    const float* b1       = (const float*)d_in[8];
    const float* w2       = (const float*)d_in[9];
    const float* b2       = (const float*)d_in[10];
    const float* w3       = (const float*)d_in[11];
    const float* b3       = (const float*)d_in[12];
    float* out = (float*)d_out;

    const int nV = in_sizes[3] / 256;                         // 50000 vertices

    char* ws = (char*)d_ws;
    _Float16* w1T  = (_Float16*)ws;                           // 229,376 B
    _Float16* w2T  = (_Float16*)(ws + 229376);                // 131,072 B
    float*    b1p  = (float*)   (ws + 360448);                // 1,024 B
    _Float16* w3T  = (_Float16*)(ws + 361472);                // 8,192 B
    _Float16* Ptab = (_Float16*)(ws + 369664);                // nV*256*2 = 25.6 MB

    hipLaunchKernelGGL(prep_weights, dim3(513), dim3(256), 0, stream,
                       style, w1, b1, w2, w3, w1T, w2T, w3T, b1p);
    hipLaunchKernelGGL(pgemm, dim3((nV + 63) / 64), dim3(256), 0, stream,
                       feature, shapef, w1T, Ptab, nV);

    const int npix = in_sizes[0];                             // 262144
    hipLaunchKernelGGL(renderer, dim3(npix / TILE_M), dim3(256), 0, stream,
                       pix, bary, faces, Ptab, color_bg,
                       b2, b3, w1T, w2T, w3T, b1p, out);
}

// Round 17
// 215.867 us; speedup vs baseline: 1.9377x; 1.9377x over previous
//
#include <hip/hip_runtime.h>
#include <math.h>

// DifferentiableMultiMLPRenderer — round 17: r13 + cross-tile pipelining.
// Each block processes 2 tiles of 64 px; tile-1's meta/gather/emb issue inside
// tile-0's layer-2 MFMA loop (pb double-buffered, embs single reused). 8-wave
// blocks at launch_bounds(512,4) (proven spill-free budget). Grid 2048.

typedef _Float16 hv8 __attribute__((ext_vector_type(8)));
typedef __attribute__((ext_vector_type(4))) float f32x4;

__device__ inline int swzE(int row, int k) { return row * 64  + (k ^ ((row & 7) << 3)); }
__device__ inline int swzH(int row, int k) { return row * 256 + (k ^ ((row & 7) << 3)); }
__device__ inline int swzA(int row, int k) { return row * 384 + (k ^ ((row & 7) << 3)); }

// ---- prep: fold style into b1; build f16 weights: w1T (1/3 folded), w2T, w3T ----
__global__ __launch_bounds__(256)
void prep_weights(const float* __restrict__ style,
                  const float* __restrict__ w1, const float* __restrict__ b1,
                  const float* __restrict__ w2, const float* __restrict__ w3,
                  _Float16* __restrict__ w1T, _Float16* __restrict__ w2T,
                  _Float16* __restrict__ w3T, float* __restrict__ b1p)
{
    const int j = blockIdx.x;
    const int t = threadIdx.x;
    if (j < 256) {
        float part = style[t] * w1[(size_t)(447 + t) * 256 + j];
        #pragma unroll
        for (int off = 32; off; off >>= 1) part += __shfl_down(part, off, 64);
        __shared__ float red[4];
        if ((t & 63) == 0) red[t >> 6] = part;
        __syncthreads();
        if (t == 0) b1p[j] = b1[j] + red[0] + red[1] + red[2] + red[3];
        for (int k = t; k < 448; k += 256) {
            float v = (k < 447) ? w1[(size_t)k * 256 + j] : 0.0f;
            if (k < 384) v *= (1.0f / 3.0f);
            w1T[(size_t)j * 448 + k] = (_Float16)v;
        }
    } else if (j < 512) {
        const int jj = j - 256;
        w2T[(size_t)jj * 256 + t] = (_Float16)w2[(size_t)t * 256 + jj];
    } else {
        #pragma unroll
        for (int r = 0; r < 16; ++r)
            w3T[r * 256 + t] = (r < 3) ? (_Float16)w3[t * 3 + r] : (_Float16)0.0f;
    }
}

// ---- pgemm: P[v][j] = sum_k [feat|shape][v][k] * w1T[j][k] (1/3 folded) ----
__global__ __launch_bounds__(256, 2)
void pgemm(const float* __restrict__ feat, const float* __restrict__ shp,
           const _Float16* __restrict__ w1T, _Float16* __restrict__ P, int nV)
{
    __shared__ _Float16 as[64 * 384];   // 48 KB
    const int tid = threadIdx.x;
    const int n0 = blockIdx.x * 64;
    const int lane = tid & 63, wv = tid >> 6;
    const int nbase = wv << 6, l15 = lane & 15, kq = lane >> 4;

    const hv8* bp[4];
    #pragma unroll
    for (int nf = 0; nf < 4; ++nf)
        bp[nf] = (const hv8*)(w1T + (size_t)(nbase + nf * 16 + l15) * 448 + (kq << 3));
    hv8 bv[3][4];
    auto loadB = [&](int t, hv8* dst) {
        #pragma unroll
        for (int nf = 0; nf < 4; ++nf) dst[nf] = bp[nf][t << 2];
    };
    loadB(0, bv[0]); loadB(1, bv[1]); loadB(2, bv[2]);

    #pragma unroll
    for (int i = 0; i < 12; ++i) {
        const int id = tid + i * 256;
        const int row = id / 48;
        const int g = id - row * 48;
        int v = n0 + row; if (v >= nV) v = nV - 1;
        const float* s = (g < 32) ? (feat + (size_t)v * 256 + g * 8)
                                  : (shp  + (size_t)v * 128 + (g - 32) * 8);
        const float4 a = ((const float4*)s)[0];
        const float4 b = ((const float4*)s)[1];
        hv8 h = { (_Float16)a.x, (_Float16)a.y, (_Float16)a.z, (_Float16)a.w,
                  (_Float16)b.x, (_Float16)b.y, (_Float16)b.z, (_Float16)b.w };
        *(hv8*)(&as[swzA(row, g * 8)]) = h;
    }
    f32x4 acc[4][4];
    #pragma unroll
    for (int mf = 0; mf < 4; ++mf)
        #pragma unroll
        for (int nf = 0; nf < 4; ++nf) acc[mf][nf] = (f32x4){0.f, 0.f, 0.f, 0.f};
    __syncthreads();

    auto loadA = [&](int t, hv8* dst) {
        #pragma unroll
        for (int mf = 0; mf < 4; ++mf)
            dst[mf] = *(const hv8*)(as + swzA(mf * 16 + l15, (t << 5) | (kq << 3)));
    };
    hv8 av[2][4];
    loadA(0, av[0]);
    #pragma unroll
    for (int t = 0; t < 12; ++t) {
        if (t + 1 < 12) loadA(t + 1, av[(t + 1) & 1]);
        const hv8* avt = av[t & 1];
        const hv8* bvt = bv[t % 3];
        __builtin_amdgcn_s_setprio(1);
        #pragma unroll
        for (int mf = 0; mf < 4; ++mf)
            #pragma unroll
            for (int nf = 0; nf < 4; ++nf)
                acc[mf][nf] = __builtin_amdgcn_mfma_f32_16x16x32_f16(avt[mf], bvt[nf], acc[mf][nf], 0, 0, 0);
        __builtin_amdgcn_s_setprio(0);
        if (t + 3 < 12) loadB(t + 3, bv[t % 3]);
    }
    #pragma unroll
    for (int mf = 0; mf < 4; ++mf)
        #pragma unroll
        for (int nf = 0; nf < 4; ++nf) {
            const int col = nbase + nf * 16 + l15;
            const int r0 = mf * 16 + (kq << 2);
            #pragma unroll
            for (int r = 0; r < 4; ++r) {
                const int v = n0 + r0 + r;
                if (v < nV) P[(size_t)v * 256 + col] = (_Float16)acc[mf][nf][r];
            }
        }
}

// ---- main fused pixel kernel: 512 thr / 8 waves; 2 tiles of 64 px per block ----
__global__ __launch_bounds__(512, 4)
void renderer(const int* __restrict__ pix, const float* __restrict__ bary,
              const int* __restrict__ faces,
              const _Float16* __restrict__ P,
              const float* __restrict__ color_bg,
              const float* __restrict__ b2g,
              const float* __restrict__ b3g,
              const _Float16* __restrict__ w1T,
              const _Float16* __restrict__ w2T,
              const _Float16* __restrict__ w3T,
              const float* __restrict__ b1p,
              float* __restrict__ out)
{
    __shared__ _Float16 pb[2][64 * 256];   // 64 KB (double-buffered)
    __shared__ _Float16 embs[64 * 64];     // 8 KB (reused across tiles)
    __shared__ int   vidx[2][64][3];
    __shared__ float bcs[2][64][3];

    const int tid = threadIdx.x;
    const int cpx = gridDim.x >> 3;
    const int bid = (blockIdx.x & 7) * cpx + (blockIdx.x >> 3);   // XCD-aware
    const int nb  = bid * 128;

    const int lane  = tid & 63;
    const int wv    = tid >> 6;          // 0..7
    const int nbase = wv << 5;           // 32 cols per wave
    const int l15   = lane & 15;
    const int kq    = lane >> 4;
    const int gp    = tid >> 5;          // 0..15
    const int c8    = (tid & 31) << 3;

    auto metaLoad = [&](int s) {
        if (tid < 64) {
            const int n = nb + (s << 6) + tid;
            const int face = pix[n];
            vidx[s][tid][0] = faces[face * 3 + 0];
            vidx[s][tid][1] = faces[face * 3 + 1];
            vidx[s][tid][2] = faces[face * 3 + 2];
            bcs[s][tid][0] = bary[n * 3 + 0];
            bcs[s][tid][1] = bary[n * 3 + 1];
            bcs[s][tid][2] = bary[n * 3 + 2];
        }
    };
    hv8 g0[3], g1[3];
    auto loadG = [&](hv8* g, int s, int b) {
        const int p = (b << 4) + gp;
        g[0] = *(const hv8*)(P + (size_t)vidx[s][p][0] * 256 + c8);
        g[1] = *(const hv8*)(P + (size_t)vidx[s][p][1] * 256 + c8);
        g[2] = *(const hv8*)(P + (size_t)vidx[s][p][2] * 256 + c8);
    };
    auto blendG = [&](hv8* g, int s, int b) {
        const int p = (b << 4) + gp;
        const _Float16 d0 = (_Float16)bcs[s][p][0];
        const _Float16 d1 = (_Float16)bcs[s][p][1];
        const _Float16 d2 = (_Float16)bcs[s][p][2];
        *(hv8*)(&pb[s][swzH(p, c8)]) = g[0] * d0 + g[1] * d1 + g[2] * d2;
    };
    auto embPhase = [&](int s) {
        const int p = tid >> 3;
        const int e8 = (tid & 7) << 3;
        const float c0 = bcs[s][p][0], c1 = bcs[s][p][1], c2 = bcs[s][p][2];
        hv8 h;
        #pragma unroll
        for (int i = 0; i < 8; ++i) {
            const int sl = e8 + i;
            float v;
            if (sl < 3) v = (sl == 0) ? c0 : ((sl == 1) ? c1 : c2);
            else if (sl < 63) {
                const int q = sl - 3;
                const int f = q / 6;
                const int rem = q - f * 6;
                const int d = (rem >= 3) ? rem - 3 : rem;
                const float bd = (d == 0) ? c0 : ((d == 1) ? c1 : c2);
                const float arg = bd * (float)(1 << f);
                v = (rem < 3) ? __sinf(arg) : __cosf(arg);
            } else v = 0.0f;
            h[i] = (_Float16)v;
        }
        *(hv8*)(&embs[swzE(p, e8)]) = h;
    };

    f32x4 acc[4][2];
    auto accB1 = [&]() {
        #pragma unroll
        for (int nf = 0; nf < 2; ++nf) {
            const float b = b1p[nbase + nf * 16 + l15];
            #pragma unroll
            for (int mf = 0; mf < 4; ++mf) acc[mf][nf] = (f32x4){b, b, b, b};
        }
    };
    auto l1mfma = [&]() {
        #pragma unroll
        for (int t = 0; t < 2; ++t) {
            hv8 ave[4], bve[2];
            #pragma unroll
            for (int nf = 0; nf < 2; ++nf)
                bve[nf] = *(const hv8*)(w1T + (size_t)(nbase + nf * 16 + l15) * 448 + 384 + (t << 5) + (kq << 3));
            #pragma unroll
            for (int mf = 0; mf < 4; ++mf)
                ave[mf] = *(const hv8*)(embs + swzE(mf * 16 + l15, (t << 5) | (kq << 3)));
            __builtin_amdgcn_s_setprio(1);
            #pragma unroll
            for (int mf = 0; mf < 4; ++mf)
                #pragma unroll
                for (int nf = 0; nf < 2; ++nf)
                    acc[mf][nf] = __builtin_amdgcn_mfma_f32_16x16x32_f16(ave[mf], bve[nf], acc[mf][nf], 0, 0, 0);
            __builtin_amdgcn_s_setprio(0);
        }
    };
    auto l1epi = [&](int s) {   // h1 = relu(acc + blend) in place; acc = b2
        #pragma unroll
        for (int mf = 0; mf < 4; ++mf)
            #pragma unroll
            for (int nf = 0; nf < 2; ++nf) {
                const int col = nbase + nf * 16 + l15;
                const int r0 = mf * 16 + (kq << 2);
                #pragma unroll
                for (int r = 0; r < 4; ++r) {
                    const int sl = swzH(r0 + r, col);
                    const float pv = (float)pb[s][sl];
                    pb[s][sl] = (_Float16)fmaxf(acc[mf][nf][r] + pv, 0.0f);
                }
                const float b = b2g[col];
                acc[mf][nf] = (f32x4){b, b, b, b};
            }
    };
    const hv8* bp2[2];
    #pragma unroll
    for (int nf = 0; nf < 2; ++nf)
        bp2[nf] = (const hv8*)(w2T + (size_t)(nbase + nf * 16 + l15) * 256 + (kq << 3));
    auto l2tile = [&](int s, int t) {
        hv8 av[4], bv[2];
        #pragma unroll
        for (int nf = 0; nf < 2; ++nf) bv[nf] = bp2[nf][t << 2];
        #pragma unroll
        for (int mf = 0; mf < 4; ++mf)
            av[mf] = *(const hv8*)(pb[s] + swzH(mf * 16 + l15, (t << 5) | (kq << 3)));
        __builtin_amdgcn_s_setprio(1);
        #pragma unroll
        for (int mf = 0; mf < 4; ++mf)
            #pragma unroll
            for (int nf = 0; nf < 2; ++nf)
                acc[mf][nf] = __builtin_amdgcn_mfma_f32_16x16x32_f16(av[mf], bv[nf], acc[mf][nf], 0, 0, 0);
        __builtin_amdgcn_s_setprio(0);
    };
    auto h2wr = [&](int s) {
        #pragma unroll
        for (int mf = 0; mf < 4; ++mf)
            #pragma unroll
            for (int nf = 0; nf < 2; ++nf) {
                const int col = nbase + nf * 16 + l15;
                const int r0 = mf * 16 + (kq << 2);
                #pragma unroll
                for (int r = 0; r < 4; ++r)
                    pb[s][swzH(r0 + r, col)] = (_Float16)fmaxf(acc[mf][nf][r], 0.0f);
            }
    };
    auto l3out = [&](int s) {
        if (wv < 4) {
            hv8 bw3[8];
            #pragma unroll
            for (int t = 0; t < 8; ++t)
                bw3[t] = *(const hv8*)(w3T + l15 * 256 + (t << 5) + (kq << 3));
            f32x4 acc3 = (f32x4){0.f, 0.f, 0.f, 0.f};
            #pragma unroll
            for (int t = 0; t < 8; ++t) {
                const hv8 a3 = *(const hv8*)(pb[s] + swzH((wv << 4) + l15, (t << 5) | (kq << 3)));
                acc3 = __builtin_amdgcn_mfma_f32_16x16x32_f16(a3, bw3[t], acc3, 0, 0, 0);
            }
            if (l15 < 4) {
                const int ch = l15;
                #pragma unroll
                for (int r = 0; r < 4; ++r) {
                    const int p = (wv << 4) + (kq << 2) + r;
                    const int n = nb + (s << 6) + p;
                    const bool m = pix[n] > 0;
                    float v;
                    if (ch == 3) v = m ? 1.0f : 0.0f;
                    else         v = m ? (fmaxf(acc3[r] + b3g[ch], 0.0f) - 1.0f)
                                       : color_bg[(n >> 16) * 3 + ch];
                    out[(size_t)n * 4 + ch] = v;
                }
            }
        }
    };

    // ================= schedule =================
    metaLoad(0);
    __syncthreads();                                   // B1: meta(0)

    loadG(g0, 0, 0); loadG(g1, 0, 1);
    embPhase(0);                                       // VALU hides gather latency
    blendG(g0, 0, 0); loadG(g0, 0, 2);
    blendG(g1, 0, 1); loadG(g1, 0, 3);
    blendG(g0, 0, 2);
    blendG(g1, 0, 3);
    accB1();
    __syncthreads();                                   // B2: pb0 blend + embs(0)

    l1mfma();
    l1epi(0);
    metaLoad(1);                                       // overlaps L1 phase
    __syncthreads();                                   // B3: h1(0) + meta(1)

    // L2(0) interleaved with tile-1 gather/emb (T14 at tile granularity)
    l2tile(0, 0); loadG(g0, 1, 0);
    l2tile(0, 1); blendG(g0, 1, 0); loadG(g1, 1, 1);
    l2tile(0, 2); blendG(g1, 1, 1); loadG(g0, 1, 2);
    l2tile(0, 3); blendG(g0, 1, 2); loadG(g1, 1, 3);
    l2tile(0, 4); blendG(g1, 1, 3);
    l2tile(0, 5); embPhase(1);
    l2tile(0, 6);
    l2tile(0, 7);
    __syncthreads();                                   // B4: L2(0) reads done; pb1+embs(1)

    h2wr(0);
    accB1();                                           // acc = b1 for tile 1
    __syncthreads();                                   // B5: h2(0)
    l3out(0);

    // tile 1 (head already fully staged)
    l1mfma();
    l1epi(1);
    __syncthreads();                                   // B6: h1(1)
    l2tile(1, 0); l2tile(1, 1); l2tile(1, 2); l2tile(1, 3);
    l2tile(1, 4); l2tile(1, 5); l2tile(1, 6); l2tile(1, 7);
    __syncthreads();                                   // B7: L2(1) reads done
    h2wr(1);
    __syncthreads();                                   // B8: h2(1)
    l3out(1);
}

extern "C" void kernel_launch(void* const* d_in, const int* in_sizes, int n_in,
                              void* d_out, int out_size, void* d_ws, size_t ws_size,
                              hipStream_t stream) {
    const int*   pix      = (const int*)  d_in[0];
    const float* bary     = (const float*)d_in[1];
    const int*   faces    = (const int*)  d_in[2];
    const float* feature  = (const float*)d_in[3];
    const float* shapef   = (const float*)d_in[4];
    const float* color_bg = (const float*)d_in[5];
    const float* style    = (const float*)d_in[6];
    const float* w1       = (const float*)d_in[7];
    const float* b1       = (const float*)d_in[8];
    const float* w2       = (const float*)d_in[9];
    const float* b2       = (const float*)d_in[10];
    const float* w3       = (const float*)d_in[11];
    const float* b3       = (const float*)d_in[12];
    float* out = (float*)d_out;

    const int nV = in_sizes[3] / 256;                         // 50000 vertices

    char* ws = (char*)d_ws;
    _Float16* w1T  = (_Float16*)ws;                           // 229,376 B
    _Float16* w2T  = (_Float16*)(ws + 229376);                // 131,072 B
    float*    b1p  = (float*)   (ws + 360448);                // 1,024 B
    _Float16* w3T  = (_Float16*)(ws + 361472);                // 8,192 B
    _Float16* Ptab = (_Float16*)(ws + 369664);                // nV*256*2 = 25.6 MB

    hipLaunchKernelGGL(prep_weights, dim3(513), dim3(256), 0, stream,
                       style, w1, b1, w2, w3, w1T, w2T, w3T, b1p);
    hipLaunchKernelGGL(pgemm, dim3((nV + 63) / 64), dim3(256), 0, stream,
                       feature, shapef, w1T, Ptab, nV);

    const int npix = in_sizes[0];                             // 262144
    hipLaunchKernelGGL(renderer, dim3(npix / 128), dim3(512), 0, stream,
                       pix, bary, faces, Ptab, color_bg,
                       b2, b3, w1T, w2T, w3T, b1p, out);
}

// Round 18
// 170.499 us; speedup vs baseline: 2.4533x; 1.2661x over previous
//
#include <hip/hip_runtime.h>
#include <math.h>

// DifferentiableMultiMLPRenderer — round 18: r13 + swapped-operand MFMA.
// D = W^T · X^T puts pixels in C-cols and consecutive hidden units in C-rows:
// epilogues become ds_read_b64/ds_write_b64 (8 vec ops vs 64 scalar), bias init
// float4, layer-3 emits one float4/pixel. Fragment LOADS identical to r13 ->
// same registers/LDS/barriers; pure VALU+LDS-op cut (~30% of VALU).

typedef _Float16 hv8 __attribute__((ext_vector_type(8)));
typedef _Float16 hv4 __attribute__((ext_vector_type(4)));
typedef __attribute__((ext_vector_type(4))) float f32x4;

#define TILE_M 64

__device__ inline int swzE(int row, int k) { return row * 64  + (k ^ ((row & 7) << 3)); }
__device__ inline int swzH(int row, int k) { return row * 256 + (k ^ ((row & 7) << 3)); }
__device__ inline int swzA(int row, int k) { return row * 384 + (k ^ ((row & 7) << 3)); }

// ---- prep: fold style into b1; build f16 weights: w1T (1/3 folded), w2T, w3T ----
__global__ __launch_bounds__(256)
void prep_weights(const float* __restrict__ style,
                  const float* __restrict__ w1, const float* __restrict__ b1,
                  const float* __restrict__ w2, const float* __restrict__ w3,
                  _Float16* __restrict__ w1T, _Float16* __restrict__ w2T,
                  _Float16* __restrict__ w3T, float* __restrict__ b1p)
{
    const int j = blockIdx.x;
    const int t = threadIdx.x;
    if (j < 256) {
        float part = style[t] * w1[(size_t)(447 + t) * 256 + j];
        #pragma unroll
        for (int off = 32; off; off >>= 1) part += __shfl_down(part, off, 64);
        __shared__ float red[4];
        if ((t & 63) == 0) red[t >> 6] = part;
        __syncthreads();
        if (t == 0) b1p[j] = b1[j] + red[0] + red[1] + red[2] + red[3];
        for (int k = t; k < 448; k += 256) {
            float v = (k < 447) ? w1[(size_t)k * 256 + j] : 0.0f;
            if (k < 384) v *= (1.0f / 3.0f);
            w1T[(size_t)j * 448 + k] = (_Float16)v;
        }
    } else if (j < 512) {
        const int jj = j - 256;
        w2T[(size_t)jj * 256 + t] = (_Float16)w2[(size_t)t * 256 + jj];
    } else {
        #pragma unroll
        for (int r = 0; r < 16; ++r)
            w3T[r * 256 + t] = (r < 3) ? (_Float16)w3[t * 3 + r] : (_Float16)0.0f;
    }
}

// ---- pgemm: P[v][j] = sum_k [feat|shape][v][k] * w1T[j][k] (1/3 folded) ----
__global__ __launch_bounds__(256, 2)
void pgemm(const float* __restrict__ feat, const float* __restrict__ shp,
           const _Float16* __restrict__ w1T, _Float16* __restrict__ P, int nV)
{
    __shared__ _Float16 as[64 * 384];   // 48 KB
    const int tid = threadIdx.x;
    const int n0 = blockIdx.x * 64;
    const int lane = tid & 63, wv = tid >> 6;
    const int nbase = wv << 6, l15 = lane & 15, kq = lane >> 4;

    const hv8* bp[4];
    #pragma unroll
    for (int nf = 0; nf < 4; ++nf)
        bp[nf] = (const hv8*)(w1T + (size_t)(nbase + nf * 16 + l15) * 448 + (kq << 3));
    hv8 bv[3][4];
    auto loadB = [&](int t, hv8* dst) {
        #pragma unroll
        for (int nf = 0; nf < 4; ++nf) dst[nf] = bp[nf][t << 2];
    };
    loadB(0, bv[0]); loadB(1, bv[1]); loadB(2, bv[2]);

    #pragma unroll
    for (int i = 0; i < 12; ++i) {
        const int id = tid + i * 256;
        const int row = id / 48;
        const int g = id - row * 48;
        int v = n0 + row; if (v >= nV) v = nV - 1;
        const float* s = (g < 32) ? (feat + (size_t)v * 256 + g * 8)
                                  : (shp  + (size_t)v * 128 + (g - 32) * 8);
        const float4 a = ((const float4*)s)[0];
        const float4 b = ((const float4*)s)[1];
        hv8 h = { (_Float16)a.x, (_Float16)a.y, (_Float16)a.z, (_Float16)a.w,
                  (_Float16)b.x, (_Float16)b.y, (_Float16)b.z, (_Float16)b.w };
        *(hv8*)(&as[swzA(row, g * 8)]) = h;
    }
    f32x4 acc[4][4];
    #pragma unroll
    for (int mf = 0; mf < 4; ++mf)
        #pragma unroll
        for (int nf = 0; nf < 4; ++nf) acc[mf][nf] = (f32x4){0.f, 0.f, 0.f, 0.f};
    __syncthreads();

    auto loadA = [&](int t, hv8* dst) {
        #pragma unroll
        for (int mf = 0; mf < 4; ++mf)
            dst[mf] = *(const hv8*)(as + swzA(mf * 16 + l15, (t << 5) | (kq << 3)));
    };
    hv8 av[2][4];
    loadA(0, av[0]);
    #pragma unroll
    for (int t = 0; t < 12; ++t) {
        if (t + 1 < 12) loadA(t + 1, av[(t + 1) & 1]);
        const hv8* avt = av[t & 1];
        const hv8* bvt = bv[t % 3];
        __builtin_amdgcn_s_setprio(1);
        #pragma unroll
        for (int mf = 0; mf < 4; ++mf)
            #pragma unroll
            for (int nf = 0; nf < 4; ++nf)
                acc[mf][nf] = __builtin_amdgcn_mfma_f32_16x16x32_f16(avt[mf], bvt[nf], acc[mf][nf], 0, 0, 0);
        __builtin_amdgcn_s_setprio(0);
        if (t + 3 < 12) loadB(t + 3, bv[t % 3]);
    }
    #pragma unroll
    for (int mf = 0; mf < 4; ++mf)
        #pragma unroll
        for (int nf = 0; nf < 4; ++nf) {
            const int col = nbase + nf * 16 + l15;
            const int r0 = mf * 16 + (kq << 2);
            #pragma unroll
            for (int r = 0; r < 4; ++r) {
                const int v = n0 + r0 + r;
                if (v < nV) P[(size_t)v * 256 + col] = (_Float16)acc[mf][nf][r];
            }
        }
}

// ---- main fused pixel kernel: 512 thr / 8 waves, swapped-operand MFMA ----
__global__ __launch_bounds__(512, 4)
void renderer(const int* __restrict__ pix, const float* __restrict__ bary,
              const int* __restrict__ faces,
              const _Float16* __restrict__ P,
              const float* __restrict__ color_bg,
              const float* __restrict__ b2g,
              const float* __restrict__ b3g,
              const _Float16* __restrict__ w1T,
              const _Float16* __restrict__ w2T,
              const _Float16* __restrict__ w3T,
              const float* __restrict__ b1p,
              float* __restrict__ out)
{
    __shared__ _Float16 embs[64 * 64];    // 8 KB
    __shared__ _Float16 pb[64 * 256];     // 32 KB: blend -> h1 (in-place) -> h2
    __shared__ int   vidx[TILE_M][3];
    __shared__ float bcs[TILE_M][3];

    const int tid = threadIdx.x;
    const int cpx = gridDim.x >> 3;
    const int bid = (blockIdx.x & 7) * cpx + (blockIdx.x >> 3);   // XCD-aware
    const int n0  = bid * TILE_M;

    const int lane  = tid & 63;
    const int wv    = tid >> 6;          // 0..7
    const int nbase = wv << 5;           // wave's 32 hidden cols
    const int l15   = lane & 15;
    const int kq    = lane >> 4;

    if (tid < TILE_M) {
        const int n = n0 + tid;
        const int face = pix[n];
        vidx[tid][0] = faces[face * 3 + 0];
        vidx[tid][1] = faces[face * 3 + 1];
        vidx[tid][2] = faces[face * 3 + 2];
        bcs[tid][0] = bary[n * 3 + 0];
        bcs[tid][1] = bary[n * 3 + 1];
        bcs[tid][2] = bary[n * 3 + 2];
    }
    __syncthreads();

    const int gp = tid >> 5;            // 0..15 : pixel within batch
    const int c8 = (tid & 31) << 3;     // col chunk (32 lanes cover a 512B row)

    // gather: 4 batches x 16 px; 2-deep ping-pong (T14)
    hv8 g0[3], g1[3];
    auto loadG = [&](hv8* g, const int b) {
        const int p = b * 16 + gp;
        g[0] = *(const hv8*)(P + (size_t)vidx[p][0] * 256 + c8);
        g[1] = *(const hv8*)(P + (size_t)vidx[p][1] * 256 + c8);
        g[2] = *(const hv8*)(P + (size_t)vidx[p][2] * 256 + c8);
    };
    auto blendG = [&](hv8* g, const int b) {
        const int p = b * 16 + gp;
        const _Float16 c0 = (_Float16)bcs[p][0];
        const _Float16 c1 = (_Float16)bcs[p][1];
        const _Float16 c2 = (_Float16)bcs[p][2];
        *(hv8*)(&pb[swzH(p, c8)]) = g[0] * c0 + g[1] * c1 + g[2] * c2;
    };

    loadG(g0, 0);
    loadG(g1, 1);

    // --- emb (NeRF embed of bary) -> embs; 8 vals/thread, one 16B store ---
    {
        const int p = tid >> 3;            // 0..63
        const int e8 = (tid & 7) << 3;     // slot base
        const float c0 = bcs[p][0], c1 = bcs[p][1], c2 = bcs[p][2];
        hv8 h;
        #pragma unroll
        for (int i = 0; i < 8; ++i) {
            const int s = e8 + i;
            float v;
            if (s < 3) v = (s == 0) ? c0 : ((s == 1) ? c1 : c2);
            else if (s < 63) {
                const int q = s - 3;
                const int f = q / 6;
                const int rem = q - f * 6;
                const int d = (rem >= 3) ? rem - 3 : rem;
                const float bd = (d == 0) ? c0 : ((d == 1) ? c1 : c2);
                const float arg = bd * (float)(1 << f);
                v = (rem < 3) ? __sinf(arg) : __cosf(arg);
            } else v = 0.0f;
            h[i] = (_Float16)v;
        }
        *(hv8*)(&embs[swzE(p, e8)]) = h;
    }

    // drain: blend b, re-issue b+2 into the freed slot
    blendG(g0, 0); loadG(g0, 2);
    blendG(g1, 1); loadG(g1, 3);
    blendG(g0, 2);
    blendG(g1, 3);

    // acc[hf][pf]: rows = 4 consecutive hidden (nbase+hf*16+kq*4+r), col = pixel
    f32x4 acc[2][4];
    #pragma unroll
    for (int hf = 0; hf < 2; ++hf) {
        const float4 bb = *(const float4*)(b1p + nbase + hf * 16 + (kq << 2));
        #pragma unroll
        for (int pf = 0; pf < 4; ++pf)
            acc[hf][pf] = (f32x4){bb.x, bb.y, bb.z, bb.w};
    }
    __syncthreads();   // embs + pb(blend) ready

    // --- layer-1 emb MFMA (2 K-tiles): A = w1T rows (weights), B = emb rows ---
    #pragma unroll
    for (int t = 0; t < 2; ++t) {
        hv8 aw[2], be[4];
        #pragma unroll
        for (int hf = 0; hf < 2; ++hf)
            aw[hf] = *(const hv8*)(w1T + (size_t)(nbase + hf * 16 + l15) * 448 + 384 + (t << 5) + (kq << 3));
        #pragma unroll
        for (int pf = 0; pf < 4; ++pf)
            be[pf] = *(const hv8*)(embs + swzE(pf * 16 + l15, (t << 5) | (kq << 3)));
        __builtin_amdgcn_s_setprio(1);
        #pragma unroll
        for (int hf = 0; hf < 2; ++hf)
            #pragma unroll
            for (int pf = 0; pf < 4; ++pf)
                acc[hf][pf] = __builtin_amdgcn_mfma_f32_16x16x32_f16(aw[hf], be[pf], acc[hf][pf], 0, 0, 0);
        __builtin_amdgcn_s_setprio(0);
    }

    // --- layer-1 epilogue: h1 = relu(acc + blend) via b64 RMW; acc = b2 (float4) ---
    #pragma unroll
    for (int hf = 0; hf < 2; ++hf) {
        const int h0 = nbase + hf * 16 + (kq << 2);
        const float4 b2v = *(const float4*)(b2g + h0);
        #pragma unroll
        for (int pf = 0; pf < 4; ++pf) {
            const int sl = swzH(pf * 16 + l15, h0);
            hv4 pv = *(hv4*)(&pb[sl]);
            hv4 hw;
            #pragma unroll
            for (int r = 0; r < 4; ++r)
                hw[r] = (_Float16)fmaxf(acc[hf][pf][r] + (float)pv[r], 0.0f);
            *(hv4*)(&pb[sl]) = hw;
            acc[hf][pf] = (f32x4){b2v.x, b2v.y, b2v.z, b2v.w};
        }
    }
    __syncthreads();   // h1 ready

    // --- layer-2: 8 K-tiles; A = w2T rows, B = h1 rows (both b128) ---
    #pragma unroll
    for (int t = 0; t < 8; ++t) {
        hv8 aw[2], bh[4];
        #pragma unroll
        for (int hf = 0; hf < 2; ++hf)
            aw[hf] = *(const hv8*)(w2T + (size_t)(nbase + hf * 16 + l15) * 256 + (t << 5) + (kq << 3));
        #pragma unroll
        for (int pf = 0; pf < 4; ++pf)
            bh[pf] = *(const hv8*)(pb + swzH(pf * 16 + l15, (t << 5) | (kq << 3)));
        __builtin_amdgcn_s_setprio(1);
        #pragma unroll
        for (int hf = 0; hf < 2; ++hf)
            #pragma unroll
            for (int pf = 0; pf < 4; ++pf)
                acc[hf][pf] = __builtin_amdgcn_mfma_f32_16x16x32_f16(aw[hf], bh[pf], acc[hf][pf], 0, 0, 0);
        __builtin_amdgcn_s_setprio(0);
    }

    __syncthreads();   // all layer-2 B-reads done
    // --- h2 = relu(acc) -> pb via b64 stores ---
    #pragma unroll
    for (int hf = 0; hf < 2; ++hf) {
        const int h0 = nbase + hf * 16 + (kq << 2);
        #pragma unroll
        for (int pf = 0; pf < 4; ++pf) {
            hv4 hw;
            #pragma unroll
            for (int r = 0; r < 4; ++r)
                hw[r] = (_Float16)fmaxf(acc[hf][pf][r], 0.0f);
            *(hv4*)(&pb[swzH(pf * 16 + l15, h0)]) = hw;
        }
    }

    // --- layer-3 A fragments (waves 0-3); latency hides under barrier wait ---
    hv8 aw3[8];
    if (wv < 4) {
        #pragma unroll
        for (int t = 0; t < 8; ++t)
            aw3[t] = *(const hv8*)(w3T + l15 * 256 + (t << 5) + (kq << 3));
    }
    __syncthreads();

    // --- layer-3: wave wv (0..3) owns pixels [wv*16, wv*16+16); float4 out ---
    if (wv < 4) {
        f32x4 acc3 = (f32x4){0.f, 0.f, 0.f, 0.f};
        #pragma unroll
        for (int t = 0; t < 8; ++t) {
            const hv8 bh = *(const hv8*)(pb + swzH((wv << 4) + l15, (t << 5) | (kq << 3)));
            acc3 = __builtin_amdgcn_mfma_f32_16x16x32_f16(aw3[t], bh, acc3, 0, 0, 0);
        }
        if (kq == 0) {   // rows 0..3 = channels
            const int n = n0 + (wv << 4) + l15;
            const bool m = pix[n] > 0;
            const int b = n >> 16;               // H*W = 65536
            float4 o4;
            o4.x = m ? (fmaxf(acc3[0] + b3g[0], 0.f) - 1.0f) : color_bg[b * 3 + 0];
            o4.y = m ? (fmaxf(acc3[1] + b3g[1], 0.f) - 1.0f) : color_bg[b * 3 + 1];
            o4.z = m ? (fmaxf(acc3[2] + b3g[2], 0.f) - 1.0f) : color_bg[b * 3 + 2];
            o4.w = m ? 1.0f : 0.0f;
            *(float4*)(out + (size_t)n * 4) = o4;
        }
    }
}

extern "C" void kernel_launch(void* const* d_in, const int* in_sizes, int n_in,
                              void* d_out, int out_size, void* d_ws, size_t ws_size,
                              hipStream_t stream) {
    const int*   pix      = (const int*)  d_in[0];
    const float* bary     = (const float*)d_in[1];
    const int*   faces    = (const int*)  d_in[2];
    const float* feature  = (const float*)d_in[3];
    const float* shapef   = (const float*)d_in[4];
    const float* color_bg = (const float*)d_in[5];
    const float* style    = (const float*)d_in[6];
    const float* w1       = (const float*)d_in[7];
    const float* b1       = (const float*)d_in[8];
    const float* w2       = (const float*)d_in[9];
    const float* b2       = (const float*)d_in[10];
    const float* w3       = (const float*)d_in[11];
    const float* b3       = (const float*)d_in[12];
    float* out = (float*)d_out;

    const int nV = in_sizes[3] / 256;                         // 50000 vertices

    char* ws = (char*)d_ws;
    _Float16* w1T  = (_Float16*)ws;                           // 229,376 B
    _Float16* w2T  = (_Float16*)(ws + 229376);                // 131,072 B
    float*    b1p  = (float*)   (ws + 360448);                // 1,024 B
    _Float16* w3T  = (_Float16*)(ws + 361472);                // 8,192 B
    _Float16* Ptab = (_Float16*)(ws + 369664);                // nV*256*2 = 25.6 MB

    hipLaunchKernelGGL(prep_weights, dim3(513), dim3(256), 0, stream,
                       style, w1, b1, w2, w3, w1T, w2T, w3T, b1p);
    hipLaunchKernelGGL(pgemm, dim3((nV + 63) / 64), dim3(256), 0, stream,
                       feature, shapef, w1T, Ptab, nV);

    const int npix = in_sizes[0];                             // 262144
    hipLaunchKernelGGL(renderer, dim3(npix / TILE_M), dim3(512), 0, stream,
                       pix, bary, faces, Ptab, color_bg,
                       b2, b3, w1T, w2T, w3T, b1p, out);
}

// Round 19
// 166.143 us; speedup vs baseline: 2.5177x; 1.0262x over previous
//
#include <hip/hip_runtime.h>
#include <math.h>

// DifferentiableMultiMLPRenderer — round 19: r18 at 3 blocks/CU.
// r18's swapped-operand MFMA cut arch VGPRs to 44 (+32 AGPR = ~76 unified),
// which now FITS the (512,6) budget (~85) that r14's 92-reg body couldn't.
// Minimal diff vs r18: renderer launch_bounds (512,4) -> (512,6).
// Gate: WRITE_SIZE ~4MB = fit (expect occupancy ~65%); >=50MB = spill, revert.

typedef _Float16 hv8 __attribute__((ext_vector_type(8)));
typedef _Float16 hv4 __attribute__((ext_vector_type(4)));
typedef __attribute__((ext_vector_type(4))) float f32x4;

#define TILE_M 64

__device__ inline int swzE(int row, int k) { return row * 64  + (k ^ ((row & 7) << 3)); }
__device__ inline int swzH(int row, int k) { return row * 256 + (k ^ ((row & 7) << 3)); }
__device__ inline int swzA(int row, int k) { return row * 384 + (k ^ ((row & 7) << 3)); }

// ---- prep: fold style into b1; build f16 weights: w1T (1/3 folded), w2T, w3T ----
__global__ __launch_bounds__(256)
void prep_weights(const float* __restrict__ style,
                  const float* __restrict__ w1, const float* __restrict__ b1,
                  const float* __restrict__ w2, const float* __restrict__ w3,
                  _Float16* __restrict__ w1T, _Float16* __restrict__ w2T,
                  _Float16* __restrict__ w3T, float* __restrict__ b1p)
{
    const int j = blockIdx.x;
    const int t = threadIdx.x;
    if (j < 256) {
        float part = style[t] * w1[(size_t)(447 + t) * 256 + j];
        #pragma unroll
        for (int off = 32; off; off >>= 1) part += __shfl_down(part, off, 64);
        __shared__ float red[4];
        if ((t & 63) == 0) red[t >> 6] = part;
        __syncthreads();
        if (t == 0) b1p[j] = b1[j] + red[0] + red[1] + red[2] + red[3];
        for (int k = t; k < 448; k += 256) {
            float v = (k < 447) ? w1[(size_t)k * 256 + j] : 0.0f;
            if (k < 384) v *= (1.0f / 3.0f);
            w1T[(size_t)j * 448 + k] = (_Float16)v;
        }
    } else if (j < 512) {
        const int jj = j - 256;
        w2T[(size_t)jj * 256 + t] = (_Float16)w2[(size_t)t * 256 + jj];
    } else {
        #pragma unroll
        for (int r = 0; r < 16; ++r)
            w3T[r * 256 + t] = (r < 3) ? (_Float16)w3[t * 3 + r] : (_Float16)0.0f;
    }
}

// ---- pgemm: P[v][j] = sum_k [feat|shape][v][k] * w1T[j][k] (1/3 folded) ----
__global__ __launch_bounds__(256, 2)
void pgemm(const float* __restrict__ feat, const float* __restrict__ shp,
           const _Float16* __restrict__ w1T, _Float16* __restrict__ P, int nV)
{
    __shared__ _Float16 as[64 * 384];   // 48 KB
    const int tid = threadIdx.x;
    const int n0 = blockIdx.x * 64;
    const int lane = tid & 63, wv = tid >> 6;
    const int nbase = wv << 6, l15 = lane & 15, kq = lane >> 4;

    const hv8* bp[4];
    #pragma unroll
    for (int nf = 0; nf < 4; ++nf)
        bp[nf] = (const hv8*)(w1T + (size_t)(nbase + nf * 16 + l15) * 448 + (kq << 3));
    hv8 bv[3][4];
    auto loadB = [&](int t, hv8* dst) {
        #pragma unroll
        for (int nf = 0; nf < 4; ++nf) dst[nf] = bp[nf][t << 2];
    };
    loadB(0, bv[0]); loadB(1, bv[1]); loadB(2, bv[2]);

    #pragma unroll
    for (int i = 0; i < 12; ++i) {
        const int id = tid + i * 256;
        const int row = id / 48;
        const int g = id - row * 48;
        int v = n0 + row; if (v >= nV) v = nV - 1;
        const float* s = (g < 32) ? (feat + (size_t)v * 256 + g * 8)
                                  : (shp  + (size_t)v * 128 + (g - 32) * 8);
        const float4 a = ((const float4*)s)[0];
        const float4 b = ((const float4*)s)[1];
        hv8 h = { (_Float16)a.x, (_Float16)a.y, (_Float16)a.z, (_Float16)a.w,
                  (_Float16)b.x, (_Float16)b.y, (_Float16)b.z, (_Float16)b.w };
        *(hv8*)(&as[swzA(row, g * 8)]) = h;
    }
    f32x4 acc[4][4];
    #pragma unroll
    for (int mf = 0; mf < 4; ++mf)
        #pragma unroll
        for (int nf = 0; nf < 4; ++nf) acc[mf][nf] = (f32x4){0.f, 0.f, 0.f, 0.f};
    __syncthreads();

    auto loadA = [&](int t, hv8* dst) {
        #pragma unroll
        for (int mf = 0; mf < 4; ++mf)
            dst[mf] = *(const hv8*)(as + swzA(mf * 16 + l15, (t << 5) | (kq << 3)));
    };
    hv8 av[2][4];
    loadA(0, av[0]);
    #pragma unroll
    for (int t = 0; t < 12; ++t) {
        if (t + 1 < 12) loadA(t + 1, av[(t + 1) & 1]);
        const hv8* avt = av[t & 1];
        const hv8* bvt = bv[t % 3];
        __builtin_amdgcn_s_setprio(1);
        #pragma unroll
        for (int mf = 0; mf < 4; ++mf)
            #pragma unroll
            for (int nf = 0; nf < 4; ++nf)
                acc[mf][nf] = __builtin_amdgcn_mfma_f32_16x16x32_f16(avt[mf], bvt[nf], acc[mf][nf], 0, 0, 0);
        __builtin_amdgcn_s_setprio(0);
        if (t + 3 < 12) loadB(t + 3, bv[t % 3]);
    }
    #pragma unroll
    for (int mf = 0; mf < 4; ++mf)
        #pragma unroll
        for (int nf = 0; nf < 4; ++nf) {
            const int col = nbase + nf * 16 + l15;
            const int r0 = mf * 16 + (kq << 2);
            #pragma unroll
            for (int r = 0; r < 4; ++r) {
                const int v = n0 + r0 + r;
                if (v < nV) P[(size_t)v * 256 + col] = (_Float16)acc[mf][nf][r];
            }
        }
}

// ---- main fused pixel kernel: 512 thr / 8 waves, swapped-operand MFMA ----
__global__ __launch_bounds__(512, 6)
void renderer(const int* __restrict__ pix, const float* __restrict__ bary,
              const int* __restrict__ faces,
              const _Float16* __restrict__ P,
              const float* __restrict__ color_bg,
              const float* __restrict__ b2g,
              const float* __restrict__ b3g,
              const _Float16* __restrict__ w1T,
              const _Float16* __restrict__ w2T,
              const _Float16* __restrict__ w3T,
              const float* __restrict__ b1p,
              float* __restrict__ out)
{
    __shared__ _Float16 embs[64 * 64];    // 8 KB
    __shared__ _Float16 pb[64 * 256];     // 32 KB: blend -> h1 (in-place) -> h2
    __shared__ int   vidx[TILE_M][3];
    __shared__ float bcs[TILE_M][3];

    const int tid = threadIdx.x;
    const int cpx = gridDim.x >> 3;
    const int bid = (blockIdx.x & 7) * cpx + (blockIdx.x >> 3);   // XCD-aware
    const int n0  = bid * TILE_M;

    const int lane  = tid & 63;
    const int wv    = tid >> 6;          // 0..7
    const int nbase = wv << 5;           // wave's 32 hidden cols
    const int l15   = lane & 15;
    const int kq    = lane >> 4;

    if (tid < TILE_M) {
        const int n = n0 + tid;
        const int face = pix[n];
        vidx[tid][0] = faces[face * 3 + 0];
        vidx[tid][1] = faces[face * 3 + 1];
        vidx[tid][2] = faces[face * 3 + 2];
        bcs[tid][0] = bary[n * 3 + 0];
        bcs[tid][1] = bary[n * 3 + 1];
        bcs[tid][2] = bary[n * 3 + 2];
    }
    __syncthreads();

    const int gp = tid >> 5;            // 0..15 : pixel within batch
    const int c8 = (tid & 31) << 3;     // col chunk (32 lanes cover a 512B row)

    // gather: 4 batches x 16 px; 2-deep ping-pong (T14)
    hv8 g0[3], g1[3];
    auto loadG = [&](hv8* g, const int b) {
        const int p = b * 16 + gp;
        g[0] = *(const hv8*)(P + (size_t)vidx[p][0] * 256 + c8);
        g[1] = *(const hv8*)(P + (size_t)vidx[p][1] * 256 + c8);
        g[2] = *(const hv8*)(P + (size_t)vidx[p][2] * 256 + c8);
    };
    auto blendG = [&](hv8* g, const int b) {
        const int p = b * 16 + gp;
        const _Float16 c0 = (_Float16)bcs[p][0];
        const _Float16 c1 = (_Float16)bcs[p][1];
        const _Float16 c2 = (_Float16)bcs[p][2];
        *(hv8*)(&pb[swzH(p, c8)]) = g[0] * c0 + g[1] * c1 + g[2] * c2;
    };

    loadG(g0, 0);
    loadG(g1, 1);

    // --- emb (NeRF embed of bary) -> embs; 8 vals/thread, one 16B store ---
    {
        const int p = tid >> 3;            // 0..63
        const int e8 = (tid & 7) << 3;     // slot base
        const float c0 = bcs[p][0], c1 = bcs[p][1], c2 = bcs[p][2];
        hv8 h;
        #pragma unroll
        for (int i = 0; i < 8; ++i) {
            const int s = e8 + i;
            float v;
            if (s < 3) v = (s == 0) ? c0 : ((s == 1) ? c1 : c2);
            else if (s < 63) {
                const int q = s - 3;
                const int f = q / 6;
                const int rem = q - f * 6;
                const int d = (rem >= 3) ? rem - 3 : rem;
                const float bd = (d == 0) ? c0 : ((d == 1) ? c1 : c2);
                const float arg = bd * (float)(1 << f);
                v = (rem < 3) ? __sinf(arg) : __cosf(arg);
            } else v = 0.0f;
            h[i] = (_Float16)v;
        }
        *(hv8*)(&embs[swzE(p, e8)]) = h;
    }

    // drain: blend b, re-issue b+2 into the freed slot
    blendG(g0, 0); loadG(g0, 2);
    blendG(g1, 1); loadG(g1, 3);
    blendG(g0, 2);
    blendG(g1, 3);

    // acc[hf][pf]: rows = 4 consecutive hidden (nbase+hf*16+kq*4+r), col = pixel
    f32x4 acc[2][4];
    #pragma unroll
    for (int hf = 0; hf < 2; ++hf) {
        const float4 bb = *(const float4*)(b1p + nbase + hf * 16 + (kq << 2));
        #pragma unroll
        for (int pf = 0; pf < 4; ++pf)
            acc[hf][pf] = (f32x4){bb.x, bb.y, bb.z, bb.w};
    }
    __syncthreads();   // embs + pb(blend) ready

    // --- layer-1 emb MFMA (2 K-tiles): A = w1T rows (weights), B = emb rows ---
    #pragma unroll
    for (int t = 0; t < 2; ++t) {
        hv8 aw[2], be[4];
        #pragma unroll
        for (int hf = 0; hf < 2; ++hf)
            aw[hf] = *(const hv8*)(w1T + (size_t)(nbase + hf * 16 + l15) * 448 + 384 + (t << 5) + (kq << 3));
        #pragma unroll
        for (int pf = 0; pf < 4; ++pf)
            be[pf] = *(const hv8*)(embs + swzE(pf * 16 + l15, (t << 5) | (kq << 3)));
        __builtin_amdgcn_s_setprio(1);
        #pragma unroll
        for (int hf = 0; hf < 2; ++hf)
            #pragma unroll
            for (int pf = 0; pf < 4; ++pf)
                acc[hf][pf] = __builtin_amdgcn_mfma_f32_16x16x32_f16(aw[hf], be[pf], acc[hf][pf], 0, 0, 0);
        __builtin_amdgcn_s_setprio(0);
    }

    // --- layer-1 epilogue: h1 = relu(acc + blend) via b64 RMW; acc = b2 (float4) ---
    #pragma unroll
    for (int hf = 0; hf < 2; ++hf) {
        const int h0 = nbase + hf * 16 + (kq << 2);
        const float4 b2v = *(const float4*)(b2g + h0);
        #pragma unroll
        for (int pf = 0; pf < 4; ++pf) {
            const int sl = swzH(pf * 16 + l15, h0);
            hv4 pv = *(hv4*)(&pb[sl]);
            hv4 hw;
            #pragma unroll
            for (int r = 0; r < 4; ++r)
                hw[r] = (_Float16)fmaxf(acc[hf][pf][r] + (float)pv[r], 0.0f);
            *(hv4*)(&pb[sl]) = hw;
            acc[hf][pf] = (f32x4){b2v.x, b2v.y, b2v.z, b2v.w};
        }
    }
    __syncthreads();   // h1 ready

    // --- layer-2: 8 K-tiles; A = w2T rows, B = h1 rows (both b128) ---
    #pragma unroll
    for (int t = 0; t < 8; ++t) {
        hv8 aw[2], bh[4];
        #pragma unroll
        for (int hf = 0; hf < 2; ++hf)
            aw[hf] = *(const hv8*)(w2T + (size_t)(nbase + hf * 16 + l15) * 256 + (t << 5) + (kq << 3));
        #pragma unroll
        for (int pf = 0; pf < 4; ++pf)
            bh[pf] = *(const hv8*)(pb + swzH(pf * 16 + l15, (t << 5) | (kq << 3)));
        __builtin_amdgcn_s_setprio(1);
        #pragma unroll
        for (int hf = 0; hf < 2; ++hf)
            #pragma unroll
            for (int pf = 0; pf < 4; ++pf)
                acc[hf][pf] = __builtin_amdgcn_mfma_f32_16x16x32_f16(aw[hf], bh[pf], acc[hf][pf], 0, 0, 0);
        __builtin_amdgcn_s_setprio(0);
    }

    __syncthreads();   // all layer-2 B-reads done
    // --- h2 = relu(acc) -> pb via b64 stores ---
    #pragma unroll
    for (int hf = 0; hf < 2; ++hf) {
        const int h0 = nbase + hf * 16 + (kq << 2);
        #pragma unroll
        for (int pf = 0; pf < 4; ++pf) {
            hv4 hw;
            #pragma unroll
            for (int r = 0; r < 4; ++r)
                hw[r] = (_Float16)fmaxf(acc[hf][pf][r], 0.0f);
            *(hv4*)(&pb[swzH(pf * 16 + l15, h0)]) = hw;
        }
    }

    // --- layer-3 A fragments (waves 0-3); latency hides under barrier wait ---
    hv8 aw3[8];
    if (wv < 4) {
        #pragma unroll
        for (int t = 0; t < 8; ++t)
            aw3[t] = *(const hv8*)(w3T + l15 * 256 + (t << 5) + (kq << 3));
    }
    __syncthreads();

    // --- layer-3: wave wv (0..3) owns pixels [wv*16, wv*16+16); float4 out ---
    if (wv < 4) {
        f32x4 acc3 = (f32x4){0.f, 0.f, 0.f, 0.f};
        #pragma unroll
        for (int t = 0; t < 8; ++t) {
            const hv8 bh = *(const hv8*)(pb + swzH((wv << 4) + l15, (t << 5) | (kq << 3)));
            acc3 = __builtin_amdgcn_mfma_f32_16x16x32_f16(aw3[t], bh, acc3, 0, 0, 0);
        }
        if (kq == 0) {   // rows 0..3 = channels
            const int n = n0 + (wv << 4) + l15;
            const bool m = pix[n] > 0;
            const int b = n >> 16;               // H*W = 65536
            float4 o4;
            o4.x = m ? (fmaxf(acc3[0] + b3g[0], 0.f) - 1.0f) : color_bg[b * 3 + 0];
            o4.y = m ? (fmaxf(acc3[1] + b3g[1], 0.f) - 1.0f) : color_bg[b * 3 + 1];
            o4.z = m ? (fmaxf(acc3[2] + b3g[2], 0.f) - 1.0f) : color_bg[b * 3 + 2];
            o4.w = m ? 1.0f : 0.0f;
            *(float4*)(out + (size_t)n * 4) = o4;
        }
    }
}

extern "C" void kernel_launch(void* const* d_in, const int* in_sizes, int n_in,
                              void* d_out, int out_size, void* d_ws, size_t ws_size,
                              hipStream_t stream) {
    const int*   pix      = (const int*)  d_in[0];
    const float* bary     = (const float*)d_in[1];
    const int*   faces    = (const int*)  d_in[2];
    const float* feature  = (const float*)d_in[3];
    const float* shapef   = (const float*)d_in[4];
    const float* color_bg = (const float*)d_in[5];
    const float* style    = (const float*)d_in[6];
    const float* w1       = (const float*)d_in[7];
    const float* b1       = (const float*)d_in[8];
    const float* w2       = (const float*)d_in[9];
    const float* b2       = (const float*)d_in[10];
    const float* w3       = (const float*)d_in[11];
    const float* b3       = (const float*)d_in[12];
    float* out = (float*)d_out;

    const int nV = in_sizes[3] / 256;                         // 50000 vertices

    char* ws = (char*)d_ws;
    _Float16* w1T  = (_Float16*)ws;                           // 229,376 B
    _Float16* w2T  = (_Float16*)(ws + 229376);                // 131,072 B
    float*    b1p  = (float*)   (ws + 360448);                // 1,024 B
    _Float16* w3T  = (_Float16*)(ws + 361472);                // 8,192 B
    _Float16* Ptab = (_Float16*)(ws + 369664);                // nV*256*2 = 25.6 MB

    hipLaunchKernelGGL(prep_weights, dim3(513), dim3(256), 0, stream,
                       style, w1, b1, w2, w3, w1T, w2T, w3T, b1p);
    hipLaunchKernelGGL(pgemm, dim3((nV + 63) / 64), dim3(256), 0, stream,
                       feature, shapef, w1T, Ptab, nV);

    const int npix = in_sizes[0];                             // 262144
    hipLaunchKernelGGL(renderer, dim3(npix / TILE_M), dim3(512), 0, stream,
                       pix, bary, faces, Ptab, color_bg,
                       b2, b3, w1T, w2T, w3T, b1p, out);
}